// Round 7
// baseline (250.934 us; speedup 1.0000x reference)
//
#include <hip/hip_runtime.h>
#include <hip/hip_bf16.h>
#include <stdint.h>

// CrossAttention: B=4 T=2048 HIN=1024 H=16 E=64
// cvt(X->bf16, scratch=d_out) + Wt transpose -> all-bf16 proj GEMM -> flash attn
// on 32x32x16 MFMA with cvt_pk+permlane32_swap P-redistribution (round 6: 84 us).
// This round (attn only, two scheduling fixes):
//  1) QK chains interleaved: ks-outer over st[2][2] -> 4 independent MFMA chains
//     (was 1 live chain of 4 dependent MFMAs -> exposed latency, MfmaUtil 36%).
//  2) Split staging wait: K gl_lds issued first, vmcnt(8) before QK (V in flight),
//     vmcnt(0) only before PV -> V latency hides under QK+exp. lsum adds tree'd.

typedef __bf16 bf16;
typedef __attribute__((ext_vector_type(8))) __bf16 bf16x8;
typedef __attribute__((ext_vector_type(4))) float f32x4;
typedef __attribute__((ext_vector_type(16))) float f32x16;
typedef __attribute__((ext_vector_type(4))) unsigned int u32x4;
typedef __attribute__((ext_vector_type(2))) unsigned int u32x2;

#define B_    4
#define T_    2048
#define HIN_  1024
#define H_    16
#define E_    64
#define NOUT_ 1024
#define LOG2E 1.4426950408889634f
#define QKSCALE 0.35355339059327373f   // 64^(-0.25)
#define QSCALE  (QKSCALE * LOG2E)      // fold log2(e) into Q so p = exp2(S) directly

__device__ __forceinline__ void gl_lds16(const void* g, void* l) {
  __builtin_amdgcn_global_load_lds((__attribute__((address_space(1))) void*)g,
                                   (__attribute__((address_space(3))) void*)l,
                                   16, 0, 0);
}

// ---- X fp32 -> bf16 ----
__global__ __launch_bounds__(256) void cvt_kernel(const float* __restrict__ Xq,
                                                  const float* __restrict__ Xkv,
                                                  bf16* __restrict__ Xb) {
  const float* src = blockIdx.y ? Xkv : Xq;
  bf16* dst = Xb + (size_t)blockIdx.y * (8192 * 1024);
  size_t i = ((size_t)blockIdx.x * 256 + threadIdx.x) * 8;
  float4 f0 = ((const float4*)(src + i))[0];
  float4 f1 = ((const float4*)(src + i))[1];
  bf16x8 t = {(bf16)f0.x, (bf16)f0.y, (bf16)f0.z, (bf16)f0.w,
              (bf16)f1.x, (bf16)f1.y, (bf16)f1.z, (bf16)f1.w};
  *(bf16x8*)(dst + i) = t;
}

// ---- W transpose + fp32->bf16: Wt[z][n][k] = W_z[k][n] ----
__global__ __launch_bounds__(256) void wt_kernel(const float* __restrict__ Wq,
                                                 const float* __restrict__ Wk,
                                                 const float* __restrict__ Wv,
                                                 bf16* __restrict__ Wt) {
  __shared__ float s[32][33];
  const int z = blockIdx.z;
  const float* W = (z == 0) ? Wq : ((z == 1) ? Wk : Wv);
  bf16* out = Wt + (size_t)z * HIN_ * NOUT_;
  const int n0 = blockIdx.x * 32, k0 = blockIdx.y * 32;
  const int tx = threadIdx.x, ty = threadIdx.y;
#pragma unroll
  for (int i = 0; i < 4; i++)
    s[ty + i * 8][tx] = W[(size_t)(k0 + ty + i * 8) * NOUT_ + n0 + tx];
  __syncthreads();
#pragma unroll
  for (int i = 0; i < 4; i++)
    out[(size_t)(n0 + ty + i * 8) * HIN_ + k0 + tx] = (bf16)s[tx][ty + i * 8];
}

// ---- QKV projection, all-bf16, 128x128 tile, BK=64 ----
__global__ __launch_bounds__(256, 4) void proj_kernel(const bf16* __restrict__ Xb,
                                                      const bf16* __restrict__ Wt,
                                                      bf16* __restrict__ Qb,
                                                      bf16* __restrict__ Kb,
                                                      bf16* __restrict__ Vtb) {
  __shared__ bf16 As[128 * 64];
  __shared__ bf16 Bs[128 * 64];
  const int z = blockIdx.z;
  const bf16* Abase = (z == 0) ? Xb : ((z == 1) ? Xb + (size_t)8192 * 1024 : Wt + (size_t)2 * HIN_ * NOUT_);
  const bf16* Bbase = (z == 0) ? Wt : ((z == 1) ? Wt + (size_t)HIN_ * NOUT_ : Xb + (size_t)8192 * 1024);
  const int mt = (z == 2) ? blockIdx.y : blockIdx.x;
  const int nt = (z == 2) ? blockIdx.x : blockIdx.y;
  const int m0 = mt * 128, n0 = nt * 128;
  const int tid = threadIdx.x;
  const int w = tid >> 6, lane = tid & 63, quad = lane >> 4, lo = lane & 15;
  const int wm = (w >> 1) * 64, wn = (w & 1) * 64;
  const int srow = w * 8 + (lane >> 3);
  const int schunk = (lane & 7) ^ (srow & 7);

  f32x4 acc[4][4] = {};

  for (int k0 = 0; k0 < HIN_; k0 += 64) {
    __syncthreads();
#pragma unroll
    for (int j = 0; j < 4; j++) {
      int row = j * 32 + srow;
      gl_lds16(Abase + (size_t)(m0 + row) * HIN_ + k0 + schunk * 8, As + (j * 32 + w * 8) * 64);
      gl_lds16(Bbase + (size_t)(n0 + row) * HIN_ + k0 + schunk * 8, Bs + (j * 32 + w * 8) * 64);
    }
    __syncthreads();
#pragma unroll
    for (int kk = 0; kk < 2; kk++) {
      bf16x8 bfrag[4], afrag[4];
#pragma unroll
      for (int j = 0; j < 4; j++) {
        int off = ((((kk << 2) + quad) ^ (lo & 7)) << 3);
        bfrag[j] = *(const bf16x8*)(Bs + (wn + j * 16 + lo) * 64 + off);
        afrag[j] = *(const bf16x8*)(As + (wm + j * 16 + lo) * 64 + off);
      }
#pragma unroll
      for (int i = 0; i < 4; i++)
#pragma unroll
        for (int j = 0; j < 4; j++)
          acc[i][j] = __builtin_amdgcn_mfma_f32_16x16x32_bf16(afrag[i], bfrag[j], acc[i][j], 0, 0, 0);
    }
  }

#pragma unroll
  for (int i = 0; i < 4; i++)
#pragma unroll
    for (int j = 0; j < 4; j++)
#pragma unroll
      for (int r = 0; r < 4; r++) {
        int m = m0 + wm + i * 16 + quad * 4 + r;
        int n = n0 + wn + j * 16 + lo;
        float v = acc[i][j][r];
        if (z == 2) {
          int h = m >> 6, e = m & 63, b = n >> 11, t = n & 2047;
          Vtb[(((size_t)b * H_ + h) * E_ + e) * T_ + t] = (bf16)v;
        } else {
          int b = m >> 11, t = m & 2047, h = n >> 6, e = n & 63;
          if (z == 0)
            Qb[(((size_t)b * H_ + h) * T_ + t) * E_ + e] = (bf16)(v * QSCALE);
          else
            Kb[(((size_t)b * H_ + h) * T_ + t) * E_ + e] = (bf16)(v * QKSCALE);
        }
      }
}

// ---- Flash attention: 1-wave blocks, 64 q/wave, 64-key tiles, 32x32x16 MFMA ----
// QK: A=K(m=t), B=Q(n=q) -> lane holds q=l31, t over 16 regs (t=(r&3)+8(r>>2)+4hi).
// P->PV-A: cvt_pk pairs + permlane32_swap. PV: A=P(m=q,k=t), B=V^T(n=e,k=t).
__global__ __launch_bounds__(64, 2) void attn_kernel(const bf16* __restrict__ Qb,
                                                     const bf16* __restrict__ Kb,
                                                     const bf16* __restrict__ Vtb,
                                                     float* __restrict__ out) {
  __shared__ bf16 Ks[64 * 64];   // [t'][e] rows 128B, chunk c stored at c^(row&7)
  __shared__ bf16 Vts[64 * 64];  // [e][t'] rows 128B, same swizzle
  const int lane = threadIdx.x & 63;
  const int l31 = lane & 31, hi = lane >> 5;
  const int bh = blockIdx.x, q0 = blockIdx.y * 64;
  const bf16* Qg = Qb + (size_t)bh * T_ * E_;
  const bf16* Kg = Kb + (size_t)bh * T_ * E_;
  const bf16* Vg = Vtb + (size_t)bh * E_ * T_;
  const int srow = lane >> 3;                 // 0..7 within 8-row staging group
  const int schunk = (lane & 7) ^ (srow & 7); // XOR'd source chunk

  // Q fragments (B-operand: n=l31 -> q, k=hi*8+j -> e), 4 k-steps of 16
  bf16x8 qf[2][4];
#pragma unroll
  for (int qb = 0; qb < 2; qb++)
#pragma unroll
    for (int ks = 0; ks < 4; ks++)
      qf[qb][ks] = *(const bf16x8*)(Qg + (size_t)(q0 + qb * 32 + l31) * E_ + ks * 16 + hi * 8);

  f32x16 acc[2][2] = {};
  float lsum[2] = {0.f, 0.f};

  for (int kt = 0; kt < T_ / 64; kt++) {
    // stage K tile first (needed by QK), then V tile (needed ~800cy later by PV)
#pragma unroll
    for (int i = 0; i < 8; i++)
      gl_lds16(Kg + (size_t)(kt * 64 + i * 8 + srow) * E_ + schunk * 8, Ks + (i * 8) * 64);
#pragma unroll
    for (int i = 0; i < 8; i++)
      gl_lds16(Vg + (size_t)(i * 8 + srow) * T_ + kt * 64 + schunk * 8, Vts + (i * 8) * 64);
    asm volatile("s_waitcnt vmcnt(8)" ::: "memory");  // K resident; V still in flight
    __builtin_amdgcn_sched_barrier(0);                 // pin K ds_reads below the wait

    // K fragments (A-operand: m=l31 -> t, k=hi*8+j -> e)
    bf16x8 kf[2][4];
#pragma unroll
    for (int tb = 0; tb < 2; tb++)
#pragma unroll
      for (int ks = 0; ks < 4; ks++)
        kf[tb][ks] = *(const bf16x8*)(Ks + (tb * 32 + l31) * 64 +
                                      (((2 * ks + hi) ^ (l31 & 7)) << 3));

    // QK: ks-outer -> 4 independent MFMA chains (latency hidden by interleave)
    f32x16 st[2][2] = {};
#pragma unroll
    for (int ks = 0; ks < 4; ks++)
#pragma unroll
      for (int tb = 0; tb < 2; tb++)
#pragma unroll
        for (int qb = 0; qb < 2; qb++)
          st[qb][tb] = __builtin_amdgcn_mfma_f32_32x32x16_bf16(kf[tb][ks], qf[qb][ks], st[qb][tb], 0, 0, 0);

    // exp2 -> packed P A-fragments
    bf16x8 pf[2][4];  // [qb][tc16]
#pragma unroll
    for (int qb = 0; qb < 2; qb++) {
#pragma unroll
      for (int tb = 0; tb < 2; tb++) {
        // lane holds S[q = qb*32+l31][t'' = tb*32 + (r&3)+8*(r>>2)+4*hi]
        float ex[16];
#pragma unroll
        for (int r = 0; r < 16; r++)
          ex[r] = __builtin_amdgcn_exp2f(st[qb][tb][r]);
        // tree-reduced local sum (depth 4, was a 16-deep serial chain)
        lsum[qb] += (((ex[0] + ex[1]) + (ex[2] + ex[3])) +
                     ((ex[4] + ex[5]) + (ex[6] + ex[7]))) +
                    (((ex[8] + ex[9]) + (ex[10] + ex[11])) +
                     ((ex[12] + ex[13]) + (ex[14] + ex[15])));
        // pack pairs: u[g][p] covers t'' = tb*32 + 8g + 4*hi + 2p + {0,1}
        unsigned int u[4][2];
#pragma unroll
        for (int g = 0; g < 4; g++)
#pragma unroll
          for (int p = 0; p < 2; p++)
            asm("v_cvt_pk_bf16_f32 %0, %1, %2"
                : "=v"(u[g][p]) : "v"(ex[4 * g + 2 * p]), "v"(ex[4 * g + 2 * p + 1]));
        // redistribute: swap(u[2c2][p], u[2c2+1][p]) -> frag tc16 = tb*2+c2
#pragma unroll
        for (int c2 = 0; c2 < 2; c2++) {
          u32x2 s0 = __builtin_amdgcn_permlane32_swap(u[2 * c2][0], u[2 * c2 + 1][0], false, false);
          u32x2 s1 = __builtin_amdgcn_permlane32_swap(u[2 * c2][1], u[2 * c2 + 1][1], false, false);
          u32x4 wv = {s0[0], s1[0], s0[1], s1[1]};
          pf[qb][tb * 2 + c2] = __builtin_bit_cast(bf16x8, wv);
        }
      }
    }

    asm volatile("s_waitcnt vmcnt(0)" ::: "memory");  // V resident (hidden under QK/exp)
    __builtin_amdgcn_sched_barrier(0);                 // pin V ds_reads below the wait

    // O += P @ V (A=P: m=l31->q, k=hi*8+j->t ; B=V^T: n=l31->e, k=hi*8+j->t)
#pragma unroll
    for (int tc = 0; tc < 4; tc++)
#pragma unroll
      for (int eb = 0; eb < 2; eb++) {
        bf16x8 vf = *(const bf16x8*)(Vts + (eb * 32 + l31) * 64 +
                                     (((2 * tc + hi) ^ (l31 & 7)) << 3));
#pragma unroll
        for (int qb = 0; qb < 2; qb++)
          acc[qb][eb] = __builtin_amdgcn_mfma_f32_32x32x16_bf16(pf[qb][tc], vf, acc[qb][eb], 0, 0, 0);
      }
  }

  // lane's regs covered half the t's; other half in lane^32
#pragma unroll
  for (int qb = 0; qb < 2; qb++)
    lsum[qb] += __shfl_xor(lsum[qb], 32);  // full sum for q = qb*32 + l31

  const int b = bh >> 4, h = bh & 15;
#pragma unroll
  for (int qb = 0; qb < 2; qb++)
#pragma unroll
    for (int r = 0; r < 16; r++) {
      int qrow = (r & 3) + 8 * (r >> 2) + 4 * hi;  // 0..31
      float linv = __builtin_amdgcn_rcpf(__shfl(lsum[qb], qrow));
      size_t t = q0 + qb * 32 + qrow;
#pragma unroll
      for (int eb = 0; eb < 2; eb++)
        out[((size_t)b * T_ + t) * NOUT_ + h * E_ + eb * 32 + l31] = acc[qb][eb][r] * linv;
    }
}

extern "C" void kernel_launch(void* const* d_in, const int* in_sizes, int n_in,
                              void* d_out, int out_size, void* d_ws, size_t ws_size,
                              hipStream_t stream) {
  const float* Xq  = (const float*)d_in[0];
  const float* Xkv = (const float*)d_in[1];
  const float* Wq  = (const float*)d_in[2];
  const float* Wk  = (const float*)d_in[3];
  const float* Wv  = (const float*)d_in[4];
  float* out = (float*)d_out;

  char* ws = (char*)d_ws;
  bf16* Qb  = (bf16*)(ws);                        // 16 MB [B][H][T][E]
  bf16* Kb  = (bf16*)(ws + ((size_t)16 << 20));   // 16 MB [B][H][T][E]
  bf16* Vtb = (bf16*)(ws + ((size_t)32 << 20));   // 16 MB [B][H][E][T]
  bf16* Wt  = (bf16*)(ws + ((size_t)48 << 20));   // 6 MB  3 x [N][K]
  bf16* Xb  = (bf16*)d_out;                       // 32 MB scratch (d_out unread until attn)

  hipLaunchKernelGGL(cvt_kernel, dim3(4096, 2), dim3(256), 0, stream, Xq, Xkv, Xb);
  hipLaunchKernelGGL(wt_kernel, dim3(32, 32, 3), dim3(32, 8), 0, stream, Wq, Wk, Wv, Wt);
  hipLaunchKernelGGL(proj_kernel, dim3(64, 8, 3), dim3(256), 0, stream, Xb, Wt, Qb, Kb, Vtb);
  hipLaunchKernelGGL(attn_kernel, dim3(64, 32), dim3(64), 0, stream, Qb, Kb, Vtb, out);
}